// Round 5
// baseline (728.940 us; speedup 1.0000x reference)
//
#include <hip/hip_runtime.h>

// Chamfer distance loss, fused single-pass brute force, fp32 VALU.
// N=65536 vertices (x), M=8192 samples (y), D=3.
// Each (n,m) pair distance computed ONCE. Per thread: 8 n-chains (row argmin
// in registers). Column mins: per-m in-thread tree (7 v_min) -> LDS, reduced
// across the block every G=8 m's (amortizes LDS latency; no per-m butterfly).
// q = d2/2 = 0.5||x||^2 + 0.5||y||^2 - x.y via negated-y precompute: 3 fma + 1 add.
// Key = (qbits & ~0x1FFF) | m: uint min == lexicographic (q, m) min.

constexpr int NP = 65536;
constexpr int MP = 8192;
constexpr int T = 8;                 // n-points per thread
constexpr int NB = NP / (256 * T);   // 32 n-group blocks
constexpr int CM = 64;               // m-chunks
constexpr int LM = MP / CM;          // 128 m per chunk
constexpr int G = 8;                 // m-group size for LDS col reduction

__device__ __forceinline__ unsigned umin32(unsigned a, unsigned b) { return a < b ? a : b; }

// ws layout (bytes):
//   [0,       NP*4)        rowkey (uint per n: qbits&~0x1FFF | argmin m)
//   [NP*4,    +MP*4)       colkey (uint per m: qbits&~0x1FFF | m)
//   [+,       +NP*16)      xp (float4: x0,x1,x2, 0.5*||x||^2)
//   [+,       +MP*16)      yp (float4: -y0,-y1,-y2, 0.5*||y||^2)

__global__ __launch_bounds__(256) void k0_init(const float* __restrict__ x,
                                               const float* __restrict__ y,
                                               unsigned* __restrict__ rowkey,
                                               unsigned* __restrict__ colkey,
                                               float4* __restrict__ xp,
                                               float4* __restrict__ yp,
                                               float* __restrict__ out) {
    int i = blockIdx.x * 256 + threadIdx.x;
    if (i < NP) {
        rowkey[i] = 0xFFFFFFFFu;
        float a = x[i * 3 + 0], b = x[i * 3 + 1], c = x[i * 3 + 2];
        xp[i] = make_float4(a, b, c, 0.5f * fmaf(a, a, fmaf(b, b, c * c)));
    }
    if (i < MP) {
        colkey[i] = 0xFFFFFFFFu;
        float a = y[i * 3 + 0], b = y[i * 3 + 1], c = y[i * 3 + 2];
        yp[i] = make_float4(-a, -b, -c, 0.5f * fmaf(a, a, fmaf(b, b, c * c)));
    }
    if (i == 0) out[0] = 0.f;
}

__global__ __launch_bounds__(256, 8) void k12_fused(const float4* __restrict__ xp,
                                                    const float4* __restrict__ yp,
                                                    unsigned* __restrict__ rowkey,
                                                    unsigned* __restrict__ colkey) {
    __shared__ unsigned colbuf[G][256];
    int t = threadIdx.x;
    int bx = blockIdx.x & (NB - 1);  // n-group
    int by = blockIdx.x / NB;        // m-chunk
    int nbase = bx * (256 * T);

    float x0[T], x1[T], x2[T], xw[T];
    unsigned kmin[T];
#pragma unroll
    for (int k = 0; k < T; ++k) {
        float4 xv = xp[nbase + t + k * 256];
        x0[k] = xv.x; x1[k] = xv.y; x2[k] = xv.z; xw[k] = xv.w;
        kmin[k] = 0xFFFFFFFFu;
    }

    int m0 = by * LM;
    for (int g = 0; g < LM / G; ++g) {
        int mg = m0 + g * G;
#pragma unroll
        for (int mm = 0; mm < G; ++mm) {
            int m = mg + mm;
            float4 yv = yp[m];  // wave-uniform -> scalar load
            unsigned key[T];
#pragma unroll
            for (int k = 0; k < T; ++k) {
                // q = 0.5*d2 >= 0 (up to rounding; tiny-negative keys lose the min)
                float q = fmaf(x0[k], yv.x,
                         fmaf(x1[k], yv.y,
                         fmaf(x2[k], yv.z, xw[k] + yv.w)));
                key[k] = (__float_as_uint(q) & 0xFFFFE000u) | (unsigned)m;
                kmin[k] = umin32(kmin[k], key[k]);
            }
            unsigned a0 = umin32(key[0], key[1]);
            unsigned a1 = umin32(key[2], key[3]);
            unsigned a2 = umin32(key[4], key[5]);
            unsigned a3 = umin32(key[6], key[7]);
            colbuf[mm][t] = umin32(umin32(a0, a1), umin32(a2, a3));
        }
        __syncthreads();
        {
            int msub = t >> 5;   // which m of the group this thread reduces
            int l = t & 31;      // 32 threads per m, contiguous within a half-wave
            const unsigned* row = &colbuf[msub][l * 8];
            uint4 r0 = *(const uint4*)(row);
            uint4 r1 = *(const uint4*)(row + 4);
            unsigned v = umin32(umin32(umin32(r0.x, r0.y), umin32(r0.z, r0.w)),
                                umin32(umin32(r1.x, r1.y), umin32(r1.z, r1.w)));
            // butterfly min within the 32-lane group (matches msub partition)
            v = umin32(v, (unsigned)__builtin_amdgcn_ds_swizzle((int)v, 0x041F));
            v = umin32(v, (unsigned)__builtin_amdgcn_ds_swizzle((int)v, 0x081F));
            v = umin32(v, (unsigned)__builtin_amdgcn_ds_swizzle((int)v, 0x101F));
            v = umin32(v, (unsigned)__builtin_amdgcn_ds_swizzle((int)v, 0x201F));
            v = umin32(v, (unsigned)__builtin_amdgcn_ds_swizzle((int)v, 0x401F));
            if (l == 0) atomicMin(&colkey[mg + msub], v);
        }
        __syncthreads();
    }
#pragma unroll
    for (int k = 0; k < T; ++k) atomicMin(&rowkey[nbase + t + k * 256], kmin[k]);
}

__global__ __launch_bounds__(256) void k3_reduce(const unsigned* __restrict__ rowkey,
                                                 const unsigned* __restrict__ colkey,
                                                 const float* __restrict__ probs,
                                                 float* __restrict__ out) {
    int i = blockIdx.x * 256 + threadIdx.x;
    float v = 0.f;
    if (i < NP) {
        unsigned k = rowkey[i];
        unsigned idx = k & 0x1FFFu;
        float dmin = 2.f * __uint_as_float(k & 0xFFFFE000u);  // d2 = 2q
        v = probs[idx] * dmin;  // l2 contribution
    } else {
        int m = i - NP;  // m < MP by grid construction
        unsigned k = colkey[m];
        float dmin = 2.f * __uint_as_float(k & 0xFFFFE000u);
        v = probs[m] * dmin;  // l1 contribution
    }
    for (int off = 32; off > 0; off >>= 1) v += __shfl_down(v, off, 64);
    __shared__ float wsum[4];
    int lane = threadIdx.x & 63;
    int w = threadIdx.x >> 6;
    if (lane == 0) wsum[w] = v;
    __syncthreads();
    if (threadIdx.x == 0) {
        atomicAdd(out, wsum[0] + wsum[1] + wsum[2] + wsum[3]);
    }
}

extern "C" void kernel_launch(void* const* d_in, const int* in_sizes, int n_in,
                              void* d_out, int out_size, void* d_ws, size_t ws_size,
                              hipStream_t stream) {
    const float* x = (const float*)d_in[0];      // [N,3]
    const float* y = (const float*)d_in[1];      // [M,3]
    const float* probs = (const float*)d_in[2];  // [M]
    float* out = (float*)d_out;

    char* ws = (char*)d_ws;
    unsigned* rowkey = (unsigned*)ws;
    unsigned* colkey = (unsigned*)(ws + (size_t)NP * 4);
    float4* xp = (float4*)(ws + (size_t)NP * 4 + (size_t)MP * 4);
    float4* yp = (float4*)(ws + (size_t)NP * 4 + (size_t)MP * 4 + (size_t)NP * 16);

    k0_init<<<NP / 256, 256, 0, stream>>>(x, y, rowkey, colkey, xp, yp, out);
    k12_fused<<<NB * CM, 256, 0, stream>>>(xp, yp, rowkey, colkey);
    k3_reduce<<<(NP + MP) / 256, 256, 0, stream>>>(rowkey, colkey, probs, out);
}

// Round 6
// 122.844 us; speedup vs baseline: 5.9339x; 5.9339x over previous
//
#include <hip/hip_runtime.h>

// Chamfer distance loss, two-phase brute force, packed-fp32 VALU.
// N=65536 vertices (x), M=8192 samples (y), D=3.
// Rows: per-n argmin over m via truncated-key uint min (key = qbits&~0x1FFF | m).
// Cols: per-m min over n, full-precision float, norms folded into epilogue.
// q = 0.5*d2 = 0.5||x||^2 + 0.5||y||^2 - x.y as 3 fma (+seed add), negated-y precompute.
// Chains packed in float2 ext-vectors -> v_pk_fma_f32 on gfx950.

constexpr int NP = 65536;
constexpr int MP = 8192;
constexpr int T = 8;                  // points per thread
constexpr int P = T / 2;              // float2 packs per thread
constexpr int NB = NP / (256 * T);    // 32 row-block groups
constexpr int CA = 32;                // m-chunks for rows: LM = 256
constexpr int LM = MP / CA;
constexpr int NBC = MP / (256 * T);   // 4 col-block groups
constexpr int CB = 256;               // n-chunks for cols: LN = 256
constexpr int LN = NP / CB;
constexpr int B1 = NB * CA;           // 1024 row blocks
constexpr int B2 = NBC * CB;          // 1024 col blocks

typedef float fv2 __attribute__((ext_vector_type(2)));

__device__ __forceinline__ fv2 vfma2(fv2 a, fv2 b, fv2 c) {
#if __has_builtin(__builtin_elementwise_fma)
    return __builtin_elementwise_fma(a, b, c);
#else
    fv2 r; r.x = fmaf(a.x, b.x, c.x); r.y = fmaf(a.y, b.y, c.y); return r;
#endif
}
__device__ __forceinline__ fv2 vmin2(fv2 a, fv2 b) {
#if __has_builtin(__builtin_elementwise_min)
    return __builtin_elementwise_min(a, b);
#else
    fv2 r; r.x = fminf(a.x, b.x); r.y = fminf(a.y, b.y); return r;
#endif
}
__device__ __forceinline__ unsigned umin32(unsigned a, unsigned b) { return a < b ? a : b; }

// ws layout (bytes):
//   [0,       NP*4)        rowkey  (uint per n: qbits&~0x1FFF | argmin m)
//   [NP*4,    +MP*4)       colbits (uint per m: float bits of min d2, clamped >=0)
//   [+,       +NP*16)      xp (float4: x0,x1,x2, 0.5*||x||^2)
//   [+,       +MP*16)      yp (float4: -y0,-y1,-y2, 0.5*||y||^2)

__global__ __launch_bounds__(256) void k0_init(const float* __restrict__ x,
                                               const float* __restrict__ y,
                                               unsigned* __restrict__ rowkey,
                                               unsigned* __restrict__ colbits,
                                               float4* __restrict__ xp,
                                               float4* __restrict__ yp,
                                               float* __restrict__ out) {
    int i = blockIdx.x * 256 + threadIdx.x;
    if (i < NP) {
        rowkey[i] = 0xFFFFFFFFu;
        float a = x[i * 3 + 0], b = x[i * 3 + 1], c = x[i * 3 + 2];
        xp[i] = make_float4(a, b, c, 0.5f * fmaf(a, a, fmaf(b, b, c * c)));
    }
    if (i < MP) {
        colbits[i] = 0x7F800000u;  // +inf
        float a = y[i * 3 + 0], b = y[i * 3 + 1], c = y[i * 3 + 2];
        yp[i] = make_float4(-a, -b, -c, 0.5f * fmaf(a, a, fmaf(b, b, c * c)));
    }
    if (i == 0) out[0] = 0.f;
}

__global__ __launch_bounds__(256, 6) void k12_pairs(const float4* __restrict__ xp,
                                                    const float4* __restrict__ yp,
                                                    unsigned* __restrict__ rowkey,
                                                    unsigned* __restrict__ colbits) {
    int t = threadIdx.x;
    if (blockIdx.x < B1) {
        // ---- rows: 8 n-chains as 4 float2 packs, scan an m-chunk ----
        int bx = blockIdx.x & (NB - 1);
        int by = blockIdx.x / NB;
        int nbase = bx * (256 * T);
        fv2 X0[P], X1[P], X2[P], XW[P];
        unsigned kmin[T];
#pragma unroll
        for (int p = 0; p < P; ++p) {
            float4 a = xp[nbase + t + (2 * p) * 256];
            float4 b = xp[nbase + t + (2 * p + 1) * 256];
            X0[p] = fv2{a.x, b.x}; X1[p] = fv2{a.y, b.y};
            X2[p] = fv2{a.z, b.z}; XW[p] = fv2{a.w, b.w};
            kmin[2 * p] = 0xFFFFFFFFu; kmin[2 * p + 1] = 0xFFFFFFFFu;
        }
        int m0 = by * LM;
#pragma unroll 2
        for (int m = m0; m < m0 + LM; ++m) {
            float4 yv = yp[m];  // wave-uniform -> scalar load
            fv2 b0 = {yv.x, yv.x}, b1 = {yv.y, yv.y}, b2 = {yv.z, yv.z};
            fv2 sw = {yv.w, yv.w};
#pragma unroll
            for (int p = 0; p < P; ++p) {
                // q = 0.5*d2 >= 0 (tiny-negative keys lose the min: harmless)
                fv2 q = vfma2(X0[p], b0, vfma2(X1[p], b1, vfma2(X2[p], b2, XW[p] + sw)));
                unsigned klo = (__float_as_uint(q.x) & 0xFFFFE000u) | (unsigned)m;
                unsigned khi = (__float_as_uint(q.y) & 0xFFFFE000u) | (unsigned)m;
                kmin[2 * p] = umin32(kmin[2 * p], klo);
                kmin[2 * p + 1] = umin32(kmin[2 * p + 1], khi);
            }
        }
#pragma unroll
        for (int p = 0; p < P; ++p) {
            atomicMin(&rowkey[nbase + t + (2 * p) * 256], kmin[2 * p]);
            atomicMin(&rowkey[nbase + t + (2 * p + 1) * 256], kmin[2 * p + 1]);
        }
    } else {
        // ---- cols: 8 m-chains as 4 float2 packs, scan an n-chunk ----
        int b = blockIdx.x - B1;
        int bx = b & (NBC - 1);
        int by = b / NBC;
        int mbase = bx * (256 * T);
        fv2 Y0[P], Y1[P], Y2[P], YW[P], DM[P];
#pragma unroll
        for (int p = 0; p < P; ++p) {
            float4 a = yp[mbase + t + (2 * p) * 256];
            float4 bq = yp[mbase + t + (2 * p + 1) * 256];
            Y0[p] = fv2{a.x, bq.x}; Y1[p] = fv2{a.y, bq.y};
            Y2[p] = fv2{a.z, bq.z}; YW[p] = fv2{a.w, bq.w};
            DM[p] = fv2{__builtin_inff(), __builtin_inff()};
        }
        int n0 = by * LN;
#pragma unroll 2
        for (int n = n0; n < n0 + LN; ++n) {
            float4 xv = xp[n];  // wave-uniform -> scalar load
            fv2 b0 = {xv.x, xv.x}, b1 = {xv.y, xv.y}, b2 = {xv.z, xv.z};
            fv2 sw = {xv.w, xv.w};
#pragma unroll
            for (int p = 0; p < P; ++p) {
                // q = 0.5||x||^2 - x.y  (0.5||y||^2 folded into epilogue)
                fv2 q = vfma2(Y0[p], b0, vfma2(Y1[p], b1, vfma2(Y2[p], b2, sw)));
                DM[p] = vmin2(DM[p], q);
            }
        }
#pragma unroll
        for (int p = 0; p < P; ++p) {
            float dlo = fmaxf(2.f * (DM[p].x + YW[p].x), 0.f);
            float dhi = fmaxf(2.f * (DM[p].y + YW[p].y), 0.f);
            atomicMin(&colbits[mbase + t + (2 * p) * 256], __float_as_uint(dlo));
            atomicMin(&colbits[mbase + t + (2 * p + 1) * 256], __float_as_uint(dhi));
        }
    }
}

__global__ __launch_bounds__(256) void k3_reduce(const unsigned* __restrict__ rowkey,
                                                 const unsigned* __restrict__ colbits,
                                                 const float* __restrict__ probs,
                                                 float* __restrict__ out) {
    int i = blockIdx.x * 256 + threadIdx.x;
    float v = 0.f;
    if (i < NP) {
        unsigned k = rowkey[i];
        unsigned idx = k & 0x1FFFu;
        float dmin = 2.f * __uint_as_float(k & 0xFFFFE000u);  // d2 = 2q
        v = probs[idx] * dmin;  // l2 contribution
    } else {
        int m = i - NP;  // m < MP by grid construction
        float dmin = __uint_as_float(colbits[m]);
        v = probs[m] * dmin;  // l1 contribution
    }
    for (int off = 32; off > 0; off >>= 1) v += __shfl_down(v, off, 64);
    __shared__ float wsum[4];
    int lane = threadIdx.x & 63;
    int w = threadIdx.x >> 6;
    if (lane == 0) wsum[w] = v;
    __syncthreads();
    if (threadIdx.x == 0) {
        atomicAdd(out, wsum[0] + wsum[1] + wsum[2] + wsum[3]);
    }
}

extern "C" void kernel_launch(void* const* d_in, const int* in_sizes, int n_in,
                              void* d_out, int out_size, void* d_ws, size_t ws_size,
                              hipStream_t stream) {
    const float* x = (const float*)d_in[0];      // [N,3]
    const float* y = (const float*)d_in[1];      // [M,3]
    const float* probs = (const float*)d_in[2];  // [M]
    float* out = (float*)d_out;

    char* ws = (char*)d_ws;
    unsigned* rowkey = (unsigned*)ws;
    unsigned* colbits = (unsigned*)(ws + (size_t)NP * 4);
    float4* xp = (float4*)(ws + (size_t)NP * 4 + (size_t)MP * 4);
    float4* yp = (float4*)(ws + (size_t)NP * 4 + (size_t)MP * 4 + (size_t)NP * 16);

    k0_init<<<NP / 256, 256, 0, stream>>>(x, y, rowkey, colbits, xp, yp, out);
    k12_pairs<<<B1 + B2, 256, 0, stream>>>(xp, yp, rowkey, colbits);
    k3_reduce<<<(NP + MP) / 256, 256, 0, stream>>>(rowkey, colbits, probs, out);
}